// Round 1
// baseline (236.794 us; speedup 1.0000x reference)
//
#include <hip/hip_runtime.h>

#define H 512
#define W 512
#define K 5
#define PAD 2
#define ROWS 16   // output rows per thread (sliding window)
#define XPT 4     // output cols per thread (one float4)

typedef float vf4 __attribute__((ext_vector_type(4)));

// block (64,4): each thread streams a 4-wide x 16-tall output column strip
// with a 5-row rolling accumulator. Input rows are read (ROWS+4)/ROWS = 1.25x
// (was 2x with the 4-row tile) -- the kernel is HBM-bound, so fetch
// amplification is the time. Clamped edge addresses (unconditional in-bounds
// loads), edge values zeroed by 0/1 multiplies, float4 loads, nontemporal
// stores interleaved through the unrolled row loop.
__global__ __launch_bounds__(256) void conv5x5_kernel(
    const float* __restrict__ X, const float* __restrict__ ker,
    float* __restrict__ out)
{
    const int tx  = threadIdx.x;                      // 0..63
    const int xb  = (blockIdx.x * 64 + tx) * XPT;     // 0,4,...,508
    const int y0  = blockIdx.y * (4 * ROWS) + threadIdx.y * ROWS;
    const int img = blockIdx.z;                       // 0..127

    const float* Xp = X   + (size_t)img * H * W;
    float*       Op = out + (size_t)img * H * W;

    float kk[K][K];
    #pragma unroll
    for (int i = 0; i < K; ++i)
        #pragma unroll
        for (int j = 0; j < K; ++j)
            kk[i][j] = ker[i * K + j];

    const int q  = xb >> 2;                           // float4 col index 0..127
    const int qL = (q == 0) ? 0 : q - 1;              // clamped: always in-bounds
    const int qR = (q == W / 4 - 1) ? q : q + 1;
    const float mLo = (q == 0) ? 0.f : 1.f;           // zero v[0],v[1] at left edge
    const float mHi = (q == W / 4 - 1) ? 0.f : 1.f;   // zero v[6],v[7] at right edge

    // 5 pending output rows, cyclic. All indices below are compile-time
    // constants after full unroll (no runtime indexing -> stays in VGPRs).
    float acc[K][XPT];
    #pragma unroll
    for (int p = 0; p < K; ++p)
        #pragma unroll
        for (int j = 0; j < XPT; ++j)
            acc[p][j] = 0.f;

    #pragma unroll
    for (int r = 0; r < ROWS + K - 1; ++r) {          // 20 input rows
        const int yr = y0 - PAD + r;
        vf4 Lv = {0.f, 0.f, 0.f, 0.f};
        vf4 Mv = {0.f, 0.f, 0.f, 0.f};
        vf4 Rv = {0.f, 0.f, 0.f, 0.f};
        if (yr >= 0 && yr < H) {                      // wave-uniform branch
            const vf4* rp = (const vf4*)(Xp + (size_t)yr * W);
            Lv = rp[qL];
            Mv = rp[q];
            Rv = rp[qR];
        }
        // window v[0..7] = input cols xb-2 .. xb+5; edge lanes zeroed by mask
        float v[8];
        v[0] = Lv.z * mLo;  v[1] = Lv.w * mLo;
        v[2] = Mv.x;  v[3] = Mv.y;  v[4] = Mv.z;  v[5] = Mv.w;
        v[6] = Rv.x * mHi;  v[7] = Rv.y * mHi;

        // input row r contributes kernel-row kr to output row o = r - kr.
        // Per output row the accumulation order is kr = 0..4, c = 0..4 --
        // identical to the previous kernel's order (same numerics).
        #pragma unroll
        for (int kr = 0; kr < K; ++kr) {
            const int o = r - kr;
            if (o >= 0 && o < ROWS) {
                const int pa = o % K;                 // compile-time
                #pragma unroll
                for (int c = 0; c < K; ++c)
                    #pragma unroll
                    for (int j = 0; j < XPT; ++j)
                        acc[pa][j] = fmaf(v[j + c], kk[kr][c], acc[pa][j]);
            }
        }

        // output row o = r-4 just received its last (kr=4) contribution
        if (r >= K - 1) {
            const int o  = r - (K - 1);
            const int pa = o % K;                     // compile-time
            vf4 st = {acc[pa][0], acc[pa][1], acc[pa][2], acc[pa][3]};
            __builtin_nontemporal_store(st, (vf4*)(Op + (size_t)(y0 + o) * W + xb));
            #pragma unroll
            for (int j = 0; j < XPT; ++j)
                acc[pa][j] = 0.f;                     // slot reused at r+1
        }
    }
}

extern "C" void kernel_launch(void* const* d_in, const int* in_sizes, int n_in,
                              void* d_out, int out_size, void* d_ws, size_t ws_size,
                              hipStream_t stream) {
    const float* X   = (const float*)d_in[0];
    const float* ker = (const float*)d_in[1];
    float* out = (float*)d_out;

    dim3 block(64, 4, 1);
    dim3 grid(W / (64 * XPT), H / (4 * ROWS), 4 * 32);  // (2, 8, 128)
    hipLaunchKernelGGL(conv5x5_kernel, grid, block, 0, stream, X, ker, out);
}